// Round 5
// baseline (404.510 us; speedup 1.0000x reference)
//
#include <hip/hip_runtime.h>
#include <hip/hip_cooperative_groups.h>
#include <math.h>

namespace cg = cooperative_groups;

#define NEARP 0.01f
#define BLUR 0.3f
#define MAX_ALPHA 0.999f
#define TILE 16
#define QCUT 32.0f     // mahalanobis^2 cutoff: culled alpha <= op*e^-16 ~ 3e-8

#define NBLK 512
#define NTHR 256

struct Params {
    const float* viewmats;
    const float* Ks;
    const float* means;
    const float* quats;
    const float* log_scales;
    const float* opac_logits;
    const float* color_logits;
    float4* ubbox;    // C*N      (m2x, m2y, r, 0)
    float4* sbbox;    // C*N      sorted
    float4* upay;     // C*N*3    f0=(m2x,m2y,iap,ibp) f1=(icp,op,cr,cg) f2=(cb,-,-,-)
    float4* spay;     // C*N*3    sorted
    float4* partial;  // C*T*nchunk*256
    float* tz;        // C*N
    float* out;       // C*H*W*3
    int N, C, W, H, tilesx, tilesy, nchunk, phase;
};

__device__ __forceinline__ float sigmoidf_(float x) {
    return 1.0f / (1.0f + expf(-x));
}

__device__ void phase_preprocess(const Params& p, int tot, int tid) {
    for (int idx = tid; idx < p.N * p.C; idx += tot) {
        int c = idx / p.N;
        int n = idx - c * p.N;

        float qw = p.quats[n * 4 + 0], qx = p.quats[n * 4 + 1];
        float qy = p.quats[n * 4 + 2], qz = p.quats[n * 4 + 3];
        float qn = rsqrtf(qw * qw + qx * qx + qy * qy + qz * qz);
        float w = qw * qn, x = qx * qn, y = qy * qn, z = qz * qn;
        float R00 = 1.0f - 2.0f * (y * y + z * z), R01 = 2.0f * (x * y - w * z), R02 = 2.0f * (x * z + w * y);
        float R10 = 2.0f * (x * y + w * z), R11 = 1.0f - 2.0f * (x * x + z * z), R12 = 2.0f * (y * z - w * x);
        float R20 = 2.0f * (x * z - w * y), R21 = 2.0f * (y * z + w * x), R22 = 1.0f - 2.0f * (x * x + y * y);

        float s0 = expf(p.log_scales[n * 3 + 0]);
        float s1 = expf(p.log_scales[n * 3 + 1]);
        float s2 = expf(p.log_scales[n * 3 + 2]);

        float M00 = R00 * s0, M01 = R01 * s1, M02 = R02 * s2;
        float M10 = R10 * s0, M11 = R11 * s1, M12 = R12 * s2;
        float M20 = R20 * s0, M21 = R21 * s1, M22 = R22 * s2;
        float C00 = M00 * M00 + M01 * M01 + M02 * M02;
        float C01 = M00 * M10 + M01 * M11 + M02 * M12;
        float C02 = M00 * M20 + M01 * M21 + M02 * M22;
        float C11 = M10 * M10 + M11 * M11 + M12 * M12;
        float C12 = M10 * M20 + M11 * M21 + M12 * M22;
        float C22 = M20 * M20 + M21 * M21 + M22 * M22;

        const float* vm = p.viewmats + c * 16;
        float V00 = vm[0], V01 = vm[1], V02 = vm[2], T0 = vm[3];
        float V10 = vm[4], V11 = vm[5], V12 = vm[6], T1 = vm[7];
        float V20 = vm[8], V21 = vm[9], V22 = vm[10], T2 = vm[11];
        float mex = p.means[n * 3 + 0], mey = p.means[n * 3 + 1], mez = p.means[n * 3 + 2];
        float tx = V00 * mex + V01 * mey + V02 * mez + T0;
        float ty = V10 * mex + V11 * mey + V12 * mez + T1;
        float tzv = V20 * mex + V21 * mey + V22 * mez + T2;

        float fx = p.Ks[c * 9 + 0], fy = p.Ks[c * 9 + 4], cx = p.Ks[c * 9 + 2], cy = p.Ks[c * 9 + 5];
        float tzs = (tzv > NEARP) ? tzv : NEARP;
        float iz = 1.0f / tzs;
        float m2x = fx * tx * iz + cx;
        float m2y = fy * ty * iz + cy;

        float A00 = V00 * C00 + V01 * C01 + V02 * C02;
        float A01 = V00 * C01 + V01 * C11 + V02 * C12;
        float A02 = V00 * C02 + V01 * C12 + V02 * C22;
        float A10 = V10 * C00 + V11 * C01 + V12 * C02;
        float A11 = V10 * C01 + V11 * C11 + V12 * C12;
        float A12 = V10 * C02 + V11 * C12 + V12 * C22;
        float A20 = V20 * C00 + V21 * C01 + V22 * C02;
        float A21 = V20 * C01 + V21 * C11 + V22 * C12;
        float A22 = V20 * C02 + V21 * C12 + V22 * C22;
        float S00 = A00 * V00 + A01 * V01 + A02 * V02;
        float S01 = A00 * V10 + A01 * V11 + A02 * V12;
        float S02 = A00 * V20 + A01 * V21 + A02 * V22;
        float S11 = A10 * V10 + A11 * V11 + A12 * V12;
        float S12 = A10 * V20 + A11 * V21 + A12 * V22;
        float S22 = A20 * V20 + A21 * V21 + A22 * V22;

        float J00 = fx * iz, J02 = -fx * tx * iz * iz;
        float J11 = fy * iz, J12 = -fy * ty * iz * iz;

        float c2_00 = J00 * J00 * S00 + 2.0f * J00 * J02 * S02 + J02 * J02 * S22;
        float c2_01 = J00 * J11 * S01 + J00 * J12 * S02 + J02 * J11 * S12 + J02 * J12 * S22;
        float c2_11 = J11 * J11 * S11 + 2.0f * J11 * J12 * S12 + J12 * J12 * S22;

        float a = c2_00 + BLUR;
        float cc = c2_11 + BLUR;
        float b = c2_01;
        float det = a * cc - b * b;
        bool valid = (tzv > NEARP) && (det > 1e-12f);

        float ia, ib, ic, op, r;
        if (valid) {
            float inv = 1.0f / det;
            ia = cc * inv;
            ib = -b * inv;
            ic = a * inv;
            op = sigmoidf_(p.opac_logits[n]);
            float lmax = 0.5f * (a + cc) + sqrtf(0.25f * (a - cc) * (a - cc) + b * b);
            r = sqrtf(QCUT * lmax);
        } else {
            ia = 0.0f; ib = 0.0f; ic = 0.0f; op = 0.0f;
            r = -1.0f;   // culled everywhere; exact contribution is 0 anyway
        }
        float cr = sigmoidf_(p.color_logits[n * 3 + 0]);
        float cg_ = sigmoidf_(p.color_logits[n * 3 + 1]);
        float cb = sigmoidf_(p.color_logits[n * 3 + 2]);

        // fold -0.5*log2(e) into conic so alpha = op * exp2(quad)
        const float KQ = 0.721347520444482f;
        float iap = -KQ * ia;
        float ibp = -2.0f * KQ * ib;
        float icp = -KQ * ic;

        int gi = c * p.N + n;
        p.ubbox[gi] = make_float4(m2x, m2y, r, 0.0f);
        p.upay[(size_t)gi * 3 + 0] = make_float4(m2x, m2y, iap, ibp);
        p.upay[(size_t)gi * 3 + 1] = make_float4(icp, op, cr, cg_);
        p.upay[(size_t)gi * 3 + 2] = make_float4(cb, 0.0f, 0.0f, 0.0f);
        p.tz[gi] = tzv;
    }
}

__device__ void phase_sort(const Params& p, int totWaves, int wave, int lane) {
    for (int w = wave; w < p.C * p.N; w += totWaves) {
        int c = w / p.N;
        int i = w - c * p.N;
        const float* tzc = p.tz + (size_t)c * p.N;
        float ti = tzc[i];
        int rank = 0;
        for (int j = lane; j < p.N; j += 64) {
            float tj = tzc[j];
            rank += (int)((tj < ti) || (tj == ti && j < i));   // stable
        }
#pragma unroll
        for (int off = 1; off < 64; off <<= 1)
            rank += __shfl_xor(rank, off, 64);
        int src = c * p.N + i;
        int dst = c * p.N + rank;
        if (lane < 3) p.spay[(size_t)dst * 3 + lane] = p.upay[(size_t)src * 3 + lane];
        if (lane == 63) p.sbbox[dst] = p.ubbox[src];
    }
}

__device__ void phase_render(const Params& p, int tid) {
    int T = p.tilesx * p.tilesy;
    int items = p.C * T * p.nchunk;
    int per = T * p.nchunk;
    int lane = threadIdx.x & 63;
    int pix = threadIdx.x;
    for (int item = blockIdx.x; item < items; item += gridDim.x) {
        int c = item / per;
        int rem = item - c * per;
        int t = rem / p.nchunk;
        int v = rem - t * p.nchunk;
        float x0 = (float)((t % p.tilesx) * TILE);
        float y0 = (float)((t / p.tilesx) * TILE);
        float x1 = x0 + (float)TILE;
        float y1 = y0 + (float)TILE;

        // ballot-cull this 64-rank chunk against the tile (all waves identical)
        int g = v * 64 + lane;
        bool pred = false;
        if (g < p.N) {
            float4 b = p.sbbox[(size_t)c * p.N + g];
            pred = (b.z >= 0.0f) &&
                   (b.x - b.z <= x1) && (b.x + b.z >= x0) &&
                   (b.y - b.z <= y1) && (b.y + b.z >= y0);
        }
        unsigned long long mask = __ballot(pred);

        float px = x0 + (float)(pix & 15) + 0.5f;
        float py = y0 + (float)(pix >> 4) + 0.5f;
        float Tr = 1.0f, accr = 0.0f, accg = 0.0f, accb = 0.0f;

        if (mask) {
            const float4* pay = p.spay + (size_t)c * p.N * 3;
            for (unsigned long long m = mask; m; m &= (m - 1)) {
                int bit = __ffsll((unsigned long long)m) - 1;   // ascending rank
                int gg = v * 64 + bit;
                float4 f0 = pay[(size_t)gg * 3 + 0];
                float4 f1 = pay[(size_t)gg * 3 + 1];
                float4 f2 = pay[(size_t)gg * 3 + 2];
                float dx = px - f0.x;
                float dy = py - f0.y;
                float quad = dx * (f0.z * dx + f0.w * dy) + f1.x * dy * dy;  // <= 0
                float alpha = fminf(f1.y * exp2f(quad), MAX_ALPHA);
                float wgt = alpha * Tr;
                accr += wgt * f1.z;
                accg += wgt * f1.w;
                accb += wgt * f2.x;
                Tr *= (1.0f - alpha);
            }
        }
        p.partial[(size_t)item * 256 + pix] = make_float4(accr, accg, accb, Tr);
    }
}

__device__ void phase_combine(const Params& p, int tot, int tid) {
    int T = p.tilesx * p.tilesy;
    int totpix = p.C * T * 256;
    for (int q = tid; q < totpix; q += tot) {
        int ct = q >> 8;
        int pix = q & 255;
        float Tr = 1.0f, r = 0.0f, g = 0.0f, b = 0.0f;
        for (int v = 0; v < p.nchunk; v++) {
            float4 ps = p.partial[((size_t)ct * p.nchunk + v) * 256 + pix];
            r += Tr * ps.x;
            g += Tr * ps.y;
            b += Tr * ps.z;
            Tr *= ps.w;
        }
        int c = ct / T;
        int t = ct - c * T;
        int x = (t % p.tilesx) * TILE + (pix & 15);
        int y = (t / p.tilesx) * TILE + (pix >> 4);
        if (x < p.W && y < p.H) {
            size_t o = (((size_t)c * p.H + y) * p.W + x) * 3;
            p.out[o + 0] = r;
            p.out[o + 1] = g;
            p.out[o + 2] = b;
        }
    }
}

__global__ void __launch_bounds__(NTHR, 2) gs_mega(Params p) {
    int tid = blockIdx.x * blockDim.x + threadIdx.x;
    int tot = gridDim.x * blockDim.x;
    int wave = tid >> 6;
    int lane = tid & 63;
    int totWaves = tot >> 6;

    if (p.phase == 0 || p.phase == 1) phase_preprocess(p, tot, tid);
    if (p.phase == 0) { __threadfence(); cg::this_grid().sync(); }
    if (p.phase == 0 || p.phase == 2) phase_sort(p, totWaves, wave, lane);
    if (p.phase == 0) { __threadfence(); cg::this_grid().sync(); }
    if (p.phase == 0 || p.phase == 3) phase_render(p, tid);
    if (p.phase == 0) { __threadfence(); cg::this_grid().sync(); }
    if (p.phase == 0 || p.phase == 4) phase_combine(p, tot, tid);
}

extern "C" void kernel_launch(void* const* d_in, const int* in_sizes, int n_in,
                              void* d_out, int out_size, void* d_ws, size_t ws_size,
                              hipStream_t stream) {
    int N = in_sizes[2] / 3;       // means: (N,3)
    int C = in_sizes[0] / 16;      // viewmats: (C,4,4)
    int pix = out_size / (C * 3);
    int W = (int)(sqrt((double)pix) + 0.5);
    int H = pix / W;
    int tilesx = (W + TILE - 1) / TILE;
    int tilesy = (H + TILE - 1) / TILE;
    int T = tilesx * tilesy;
    int nchunk = (N + 63) / 64;

    Params prm;
    prm.viewmats = (const float*)d_in[0];
    prm.Ks = (const float*)d_in[1];
    prm.means = (const float*)d_in[2];
    prm.quats = (const float*)d_in[3];
    prm.log_scales = (const float*)d_in[4];
    prm.opac_logits = (const float*)d_in[5];
    prm.color_logits = (const float*)d_in[6];
    prm.out = (float*)d_out;

    float4* ws4 = (float4*)d_ws;
    prm.ubbox = ws4;                                   // C*N
    prm.sbbox = prm.ubbox + (size_t)C * N;             // C*N
    prm.upay = prm.sbbox + (size_t)C * N;              // C*N*3
    prm.spay = prm.upay + (size_t)C * N * 3;           // C*N*3
    prm.partial = prm.spay + (size_t)C * N * 3;        // C*T*nchunk*256
    prm.tz = (float*)(prm.partial + (size_t)C * T * nchunk * 256);  // C*N

    prm.N = N; prm.C = C; prm.W = W; prm.H = H;
    prm.tilesx = tilesx; prm.tilesy = tilesy; prm.nchunk = nchunk;
    prm.phase = 0;

    void* args[] = { &prm };
    hipError_t err = hipLaunchCooperativeKernel((void*)gs_mega, dim3(NBLK), dim3(NTHR),
                                                args, 0, stream);
    if (err != hipSuccess) {
        // fallback: same kernel, 4 sequential phase launches (stream order = sync)
        for (int ph = 1; ph <= 4; ph++) {
            Params pp = prm;
            pp.phase = ph;
            hipLaunchKernelGGL(gs_mega, dim3(NBLK), dim3(NTHR), 0, stream, pp);
        }
    }
}

// Round 6
// 105.613 us; speedup vs baseline: 3.8301x; 3.8301x over previous
//
#include <hip/hip_runtime.h>
#include <hip/hip_fp16.h>
#include <math.h>

#define NEARP 0.01f
#define BLUR 0.3f
#define MAX_ALPHA 0.999f
#define TILE 16
#define NSEG 16
#define QCUT 32.0f   // mahalanobis^2 cutoff: culled alpha <= op*e^-16 ~ 1e-7

__device__ __forceinline__ float sigmoidf_(float x) {
    return 1.0f / (1.0f + expf(-x));
}

// ---------------------------------------------------------------------------
// Stage 1: preprocess -> bbox float4 (m2x,m2y,r,-) + payload 2x float4 + tz
// payload: f0=(m2x, m2y, iap, ibp)  f1=(icp, op, rg_half2, b)
// conic pre-scaled by -0.5*log2(e): alpha = op * exp2(quad')
// ---------------------------------------------------------------------------
__global__ void gs_preprocess(const float* __restrict__ viewmats,
                              const float* __restrict__ Ks,
                              const float* __restrict__ means,
                              const float* __restrict__ quats,
                              const float* __restrict__ log_scales,
                              const float* __restrict__ opac_logits,
                              const float* __restrict__ color_logits,
                              float4* __restrict__ ubbox,
                              float4* __restrict__ upay,
                              float* __restrict__ tz_out,
                              int N, int C) {
    int idx = blockIdx.x * blockDim.x + threadIdx.x;
    if (idx >= N * C) return;
    int c = idx / N;
    int n = idx - c * N;

    float qw = quats[n * 4 + 0], qx = quats[n * 4 + 1];
    float qy = quats[n * 4 + 2], qz = quats[n * 4 + 3];
    float qn = rsqrtf(qw * qw + qx * qx + qy * qy + qz * qz);
    float w = qw * qn, x = qx * qn, y = qy * qn, z = qz * qn;
    float R00 = 1.0f - 2.0f * (y * y + z * z), R01 = 2.0f * (x * y - w * z), R02 = 2.0f * (x * z + w * y);
    float R10 = 2.0f * (x * y + w * z), R11 = 1.0f - 2.0f * (x * x + z * z), R12 = 2.0f * (y * z - w * x);
    float R20 = 2.0f * (x * z - w * y), R21 = 2.0f * (y * z + w * x), R22 = 1.0f - 2.0f * (x * x + y * y);

    float s0 = expf(log_scales[n * 3 + 0]);
    float s1 = expf(log_scales[n * 3 + 1]);
    float s2 = expf(log_scales[n * 3 + 2]);

    float M00 = R00 * s0, M01 = R01 * s1, M02 = R02 * s2;
    float M10 = R10 * s0, M11 = R11 * s1, M12 = R12 * s2;
    float M20 = R20 * s0, M21 = R21 * s1, M22 = R22 * s2;
    float C00 = M00 * M00 + M01 * M01 + M02 * M02;
    float C01 = M00 * M10 + M01 * M11 + M02 * M12;
    float C02 = M00 * M20 + M01 * M21 + M02 * M22;
    float C11 = M10 * M10 + M11 * M11 + M12 * M12;
    float C12 = M10 * M20 + M11 * M21 + M12 * M22;
    float C22 = M20 * M20 + M21 * M21 + M22 * M22;

    const float* vm = viewmats + c * 16;
    float V00 = vm[0], V01 = vm[1], V02 = vm[2], T0 = vm[3];
    float V10 = vm[4], V11 = vm[5], V12 = vm[6], T1 = vm[7];
    float V20 = vm[8], V21 = vm[9], V22 = vm[10], T2 = vm[11];
    float mex = means[n * 3 + 0], mey = means[n * 3 + 1], mez = means[n * 3 + 2];
    float tx = V00 * mex + V01 * mey + V02 * mez + T0;
    float ty = V10 * mex + V11 * mey + V12 * mez + T1;
    float tz = V20 * mex + V21 * mey + V22 * mez + T2;

    float fx = Ks[c * 9 + 0], fy = Ks[c * 9 + 4], cx = Ks[c * 9 + 2], cy = Ks[c * 9 + 5];
    float tzs = (tz > NEARP) ? tz : NEARP;
    float iz = 1.0f / tzs;
    float m2x = fx * tx * iz + cx;
    float m2y = fy * ty * iz + cy;

    float A00 = V00 * C00 + V01 * C01 + V02 * C02;
    float A01 = V00 * C01 + V01 * C11 + V02 * C12;
    float A02 = V00 * C02 + V01 * C12 + V02 * C22;
    float A10 = V10 * C00 + V11 * C01 + V12 * C02;
    float A11 = V10 * C01 + V11 * C11 + V12 * C12;
    float A12 = V10 * C02 + V11 * C12 + V12 * C22;
    float A20 = V20 * C00 + V21 * C01 + V22 * C02;
    float A21 = V20 * C01 + V21 * C11 + V22 * C12;
    float A22 = V20 * C02 + V21 * C12 + V22 * C22;
    float S00 = A00 * V00 + A01 * V01 + A02 * V02;
    float S01 = A00 * V10 + A01 * V11 + A02 * V12;
    float S02 = A00 * V20 + A01 * V21 + A02 * V22;
    float S11 = A10 * V10 + A11 * V11 + A12 * V12;
    float S12 = A10 * V20 + A11 * V21 + A12 * V22;
    float S22 = A20 * V20 + A21 * V21 + A22 * V22;

    float J00 = fx * iz, J02 = -fx * tx * iz * iz;
    float J11 = fy * iz, J12 = -fy * ty * iz * iz;

    float c2_00 = J00 * J00 * S00 + 2.0f * J00 * J02 * S02 + J02 * J02 * S22;
    float c2_01 = J00 * J11 * S01 + J00 * J12 * S02 + J02 * J11 * S12 + J02 * J12 * S22;
    float c2_11 = J11 * J11 * S11 + 2.0f * J11 * J12 * S12 + J12 * J12 * S22;

    float a = c2_00 + BLUR;
    float cc = c2_11 + BLUR;
    float b = c2_01;
    float det = a * cc - b * b;
    bool valid = (tz > NEARP) && (det > 1e-12f);

    float ia, ib, ic, op, r;
    if (valid) {
        float inv = 1.0f / det;
        ia = cc * inv;
        ib = -b * inv;
        ic = a * inv;
        op = sigmoidf_(opac_logits[n]);
        float lmax = 0.5f * (a + cc) + sqrtf(0.25f * (a - cc) * (a - cc) + b * b);
        r = sqrtf(QCUT * lmax);
    } else {
        ia = 0.0f; ib = 0.0f; ic = 0.0f; op = 0.0f;
        r = -1.0f;  // culled from every tile; exact contribution is 0 anyway
    }
    float cr = sigmoidf_(color_logits[n * 3 + 0]);
    float cg = sigmoidf_(color_logits[n * 3 + 1]);
    float cb = sigmoidf_(color_logits[n * 3 + 2]);

    const float KQ = 0.721347520444482f;   // 0.5*log2(e)
    float iap = -KQ * ia;
    float ibp = -2.0f * KQ * ib;
    float icp = -KQ * ic;

    union { __half2 h; float f; } pk;
    pk.h = __floats2half2_rn(cr, cg);

    int gi = c * N + n;
    ubbox[gi] = make_float4(m2x, m2y, r, 0.0f);
    upay[(size_t)gi * 2 + 0] = make_float4(m2x, m2y, iap, ibp);
    upay[(size_t)gi * 2 + 1] = make_float4(icp, op, pk.f, cb);
    tz_out[gi] = tz;
}

// ---------------------------------------------------------------------------
// Stage 2: wave-per-element stable rank sort; scatter bbox + payload to rank.
// ---------------------------------------------------------------------------
__global__ void gs_sort_wave(const float4* __restrict__ ubbox,
                             const float4* __restrict__ upay,
                             const float* __restrict__ tzin,
                             float4* __restrict__ sbbox,
                             float4* __restrict__ spay,
                             int N, int C) {
    int gtid = blockIdx.x * blockDim.x + threadIdx.x;
    int wid = gtid >> 6;
    int lane = gtid & 63;
    if (wid >= C * N) return;
    int c = wid / N;
    int i = wid - c * N;
    const float* tzc = tzin + (size_t)c * N;
    float ti = tzc[i];
    int rank = 0;
    for (int j = lane; j < N; j += 64) {
        float tj = tzc[j];
        rank += (int)((tj < ti) || (tj == ti && j < i));  // stable
    }
#pragma unroll
    for (int off = 1; off < 64; off <<= 1)
        rank += __shfl_xor(rank, off, 64);
    int src = c * N + i;
    int dst = c * N + rank;
    if (lane == 0) sbbox[dst] = ubbox[src];
    if (lane < 2) spay[(size_t)dst * 2 + lane] = upay[(size_t)src * 2 + lane];
}

// ---------------------------------------------------------------------------
// Stage 3: render with fused ballot-cull. Block = (tile, seg); seg covers a
// contiguous range of 64-rank chunks. Per chunk: lanes test bboxes vs tile,
// wave walks surviving bits in ascending-rank order. No LDS, no barriers.
// ---------------------------------------------------------------------------
__global__ void __launch_bounds__(256) gs_render_seg(const float4* __restrict__ sbbox,
                                                     const float4* __restrict__ spay,
                                                     float4* __restrict__ partial,
                                                     int N, int W, int H,
                                                     int tilesx, int nseg, int cps) {
    int zc = blockIdx.z;                 // zc = c*nseg + s
    int c = zc / nseg;
    int s = zc - c * nseg;
    int nchunk = (N + 63) >> 6;
    int v0 = s * cps;
    int v1 = min(nchunk, v0 + cps);

    float x0 = (float)(blockIdx.x * TILE);
    float y0 = (float)(blockIdx.y * TILE);
    float x1 = x0 + (float)TILE;
    float y1 = y0 + (float)TILE;

    int lane = threadIdx.x & 63;
    float px = x0 + (float)(threadIdx.x & 15) + 0.5f;
    float py = y0 + (float)(threadIdx.x >> 4) + 0.5f;

    float Tr = 1.0f, accr = 0.0f, accg = 0.0f, accb = 0.0f;
    const float4* bb = sbbox + (size_t)c * N;
    const float4* pay = spay + (size_t)c * N * 2;

    for (int v = v0; v < v1; v++) {
        int g = v * 64 + lane;
        bool pred = false;
        if (g < N) {
            float4 b = bb[g];
            pred = (b.z >= 0.0f) &&
                   (b.x - b.z <= x1) && (b.x + b.z >= x0) &&
                   (b.y - b.z <= y1) && (b.y + b.z >= y0);
        }
        unsigned long long m = __ballot(pred);
        for (; m; m &= (m - 1)) {
            int gg = v * 64 + (__ffsll((unsigned long long)m) - 1);  // asc rank
            float4 f0 = pay[(size_t)gg * 2 + 0];
            float4 f1 = pay[(size_t)gg * 2 + 1];
            float dx = px - f0.x;
            float dy = py - f0.y;
            float quad = dx * (f0.z * dx + f0.w * dy) + f1.x * dy * dy;  // <= 0
            float alpha = fminf(f1.y * exp2f(quad), MAX_ALPHA);
            union { float f; __half2 h; } pk; pk.f = f1.z;
            float wgt = alpha * Tr;
            accr += wgt * __low2float(pk.h);
            accg += wgt * __high2float(pk.h);
            accb += wgt * f1.w;
            Tr *= (1.0f - alpha);
        }
    }
    // partial layout: [zc][256] tile-local (combine re-derives pixel coords)
    partial[((size_t)(c * nseg + s) * gridDim.x * gridDim.y +
             (size_t)(blockIdx.y * gridDim.x + blockIdx.x)) * 256 + threadIdx.x] =
        make_float4(accr, accg, accb, Tr);
}

// ---------------------------------------------------------------------------
// Stage 4: fold nseg partials per pixel, in segment order.
// ---------------------------------------------------------------------------
__global__ void gs_combine(const float4* __restrict__ partial,
                           float* __restrict__ out,
                           int W, int H, int tilesx, int tilesy, int nseg, int C) {
    int q = blockIdx.x * blockDim.x + threadIdx.x;
    int T = tilesx * tilesy;
    if (q >= C * T * 256) return;
    int pix = q & 255;
    int ct = q >> 8;
    int c = ct / T;
    int t = ct - c * T;

    float Tr = 1.0f, r = 0.0f, g = 0.0f, b = 0.0f;
    for (int s = 0; s < nseg; s++) {
        float4 ps = partial[((size_t)(c * nseg + s) * T + t) * 256 + pix];
        r += Tr * ps.x;
        g += Tr * ps.y;
        b += Tr * ps.z;
        Tr *= ps.w;
    }
    int x = (t % tilesx) * TILE + (pix & 15);
    int y = (t / tilesx) * TILE + (pix >> 4);
    if (x < W && y < H) {
        size_t o = (((size_t)c * H + y) * W + x) * 3;
        out[o + 0] = r;
        out[o + 1] = g;
        out[o + 2] = b;
    }
}

extern "C" void kernel_launch(void* const* d_in, const int* in_sizes, int n_in,
                              void* d_out, int out_size, void* d_ws, size_t ws_size,
                              hipStream_t stream) {
    const float* viewmats = (const float*)d_in[0];
    const float* Ks = (const float*)d_in[1];
    const float* means = (const float*)d_in[2];
    const float* quats = (const float*)d_in[3];
    const float* log_scales = (const float*)d_in[4];
    const float* opac_logits = (const float*)d_in[5];
    const float* color_logits = (const float*)d_in[6];
    float* out = (float*)d_out;

    int N = in_sizes[2] / 3;       // means: (N,3)
    int C = in_sizes[0] / 16;      // viewmats: (C,4,4)
    int pix = out_size / (C * 3);
    int W = (int)(sqrt((double)pix) + 0.5);
    int H = pix / W;
    int tilesx = (W + TILE - 1) / TILE;
    int tilesy = (H + TILE - 1) / TILE;
    int T = tilesx * tilesy;
    int nseg = NSEG;
    int nchunk = (N + 63) / 64;
    int cps = (nchunk + nseg - 1) / nseg;   // chunks per segment

    // workspace layout (16B-aligned chunks)
    float4* ubbox = (float4*)d_ws;                        // C*N
    float4* sbbox = ubbox + (size_t)C * N;                // C*N
    float4* upay  = sbbox + (size_t)C * N;                // C*N*2
    float4* spay  = upay + (size_t)C * N * 2;             // C*N*2
    float4* partial = spay + (size_t)C * N * 2;           // C*nseg*T*256
    float*  tzbuf = (float*)(partial + (size_t)C * nseg * T * 256);  // C*N

    int total = C * N;
    gs_preprocess<<<(total + 255) / 256, 256, 0, stream>>>(
        viewmats, Ks, means, quats, log_scales, opac_logits, color_logits,
        ubbox, upay, tzbuf, N, C);

    gs_sort_wave<<<(total * 64 + 255) / 256, 256, 0, stream>>>(
        ubbox, upay, tzbuf, sbbox, spay, N, C);

    dim3 grid(tilesx, tilesy, C * nseg);
    gs_render_seg<<<grid, 256, 0, stream>>>(
        sbbox, spay, partial, N, W, H, tilesx, nseg, cps);

    int cq = C * T * 256;
    gs_combine<<<(cq + 255) / 256, 256, 0, stream>>>(
        partial, out, W, H, tilesx, tilesy, nseg, C);
}